// Round 1
// baseline (986.810 us; speedup 1.0000x reference)
//
#include <hip/hip_runtime.h>
#include <hip/hip_bf16.h>
#include <cstddef>

typedef unsigned short u16;
typedef u16 u16x8 __attribute__((ext_vector_type(8)));
typedef __bf16 bf16x8 __attribute__((ext_vector_type(8)));
typedef float f32x4 __attribute__((ext_vector_type(4)));

__device__ __forceinline__ u16 f2b(float f) {
  unsigned int u = __float_as_uint(f);
  unsigned int r = 0x7FFFu + ((u >> 16) & 1u);
  return (u16)((u + r) >> 16);
}
__device__ __forceinline__ float b2f(u16 u) {
  return __uint_as_float(((unsigned int)u) << 16);
}

// ---------------- bf16 MFMA GEMM: C[M,256] = A[M,K](fp32) @ Wt[256,K](bf16)^T --------
// 128x128 tile, 256 threads = 4 waves in 2x2 quadrants of 64x64.
// A conversion fp32->bf16 fused into LDS staging. XOR-swizzled LDS (c ^= row&7)
// keeps ds_read_b128 at the 8-cycle floor.
template <bool OUT_BF16>
__global__ __launch_bounds__(256) void gemm_bf16(
    const float* __restrict__ A, const u16* __restrict__ Bt, void* __restrict__ Cv,
    int M, int K) {
  __shared__ u16 As[128 * 64];
  __shared__ u16 Bs[128 * 64];
  const int tid = threadIdx.x;
  const int wid = tid >> 6;
  const int lane = tid & 63;
  const int brow = blockIdx.y * 128;
  const int bcol = blockIdx.x * 128;
  const int waveM = (wid >> 1) * 64;
  const int waveN = (wid & 1) * 64;
  const int q = lane >> 4;
  const int rl = lane & 15;

  f32x4 acc[4][4] = {};

  const int arow = tid >> 1;         // 0..127
  const int khalf = (tid & 1) * 32;  // element offset within 64-chunk
  const int garow = brow + arow;
  const bool aok = garow < M;
  const int swz = arow & 7;

  for (int k0 = 0; k0 < K; k0 += 64) {
    {  // stage A (fp32 -> bf16)
      const float* src = A + (size_t)garow * K + k0 + khalf;
      u16* dstrow = As + arow * 64;
#pragma unroll
      for (int j = 0; j < 4; ++j) {
        float4 v0 = make_float4(0.f, 0.f, 0.f, 0.f), v1 = v0;
        if (aok) {
          v0 = *(const float4*)(src + j * 8);
          v1 = *(const float4*)(src + j * 8 + 4);
        }
        u16x8 v = {f2b(v0.x), f2b(v0.y), f2b(v0.z), f2b(v0.w),
                   f2b(v1.x), f2b(v1.y), f2b(v1.z), f2b(v1.w)};
        const int c = (khalf >> 3) + j;
        *(u16x8*)(dstrow + 8 * (c ^ swz)) = v;
      }
    }
    {  // stage Bt (already bf16); Bt row = bcol + arow, always < 256
      const u16* src = Bt + (size_t)(bcol + arow) * K + k0 + khalf;
      u16* dstrow = Bs + arow * 64;
#pragma unroll
      for (int j = 0; j < 4; ++j) {
        u16x8 v = *(const u16x8*)(src + j * 8);
        const int c = (khalf >> 3) + j;
        *(u16x8*)(dstrow + 8 * (c ^ swz)) = v;
      }
    }
    __syncthreads();
#pragma unroll
    for (int ks = 0; ks < 2; ++ks) {
      bf16x8 af[4], bfr[4];
      const int cbase = ks * 4 + q;
#pragma unroll
      for (int i = 0; i < 4; ++i) {
        const int r = waveM + 16 * i + rl;
        af[i] = __builtin_bit_cast(bf16x8,
                 *(const u16x8*)(As + r * 64 + 8 * (cbase ^ (rl & 7))));
      }
#pragma unroll
      for (int j = 0; j < 4; ++j) {
        const int r = waveN + 16 * j + rl;
        bfr[j] = __builtin_bit_cast(bf16x8,
                  *(const u16x8*)(Bs + r * 64 + 8 * (cbase ^ (rl & 7))));
      }
#pragma unroll
      for (int i = 0; i < 4; ++i)
#pragma unroll
        for (int j = 0; j < 4; ++j)
          acc[i][j] = __builtin_amdgcn_mfma_f32_16x16x32_bf16(af[i], bfr[j], acc[i][j], 0, 0, 0);
    }
    __syncthreads();
  }

  // epilogue: C/D layout col=lane&15, row=quad*4+reg (m89/m91-verified)
#pragma unroll
  for (int i = 0; i < 4; ++i) {
#pragma unroll
    for (int reg = 0; reg < 4; ++reg) {
      const int gr = brow + waveM + 16 * i + q * 4 + reg;
      if (gr >= M) continue;
#pragma unroll
      for (int j = 0; j < 4; ++j) {
        const int col = bcol + waveN + 16 * j + rl;
        const float v = acc[i][j][reg];
        if (OUT_BF16) ((u16*)Cv)[(size_t)gr * 256 + col] = f2b(v);
        else          ((float*)Cv)[(size_t)gr * 256 + col] = v;
      }
    }
  }
}

// ---------------- W[K][256] fp32 -> Wt[256][K] bf16 ----------------
__global__ __launch_bounds__(256) void conv_wt(const float* __restrict__ W,
                                               u16* __restrict__ Wt, int K) {
  const int idx = blockIdx.x * 256 + threadIdx.x;  // over K*256
  const int k = idx >> 8;
  const int n = idx & 255;
  if (k < K) Wt[(size_t)n * K + k] = f2b(W[idx]);
}

// ---------------- CSR build ----------------
__global__ __launch_bounds__(256) void zero_i32(int* __restrict__ p, int n) {
  int i = blockIdx.x * 256 + threadIdx.x;
  if (i < n) p[i] = 0;
}

__global__ __launch_bounds__(256) void hist_rows(const int* __restrict__ row,
                                                 int* __restrict__ deg, int E) {
  int e = blockIdx.x * 256 + threadIdx.x;
  if (e < E) atomicAdd(&deg[row[e]], 1);
}

__global__ __launch_bounds__(256) void scan1(const int* __restrict__ deg,
                                             int* __restrict__ offs,
                                             int* __restrict__ partials, int n) {
  __shared__ int sh[256];
  const int t = threadIdx.x;
  const int base = blockIdx.x * 1024 + t * 4;
  int v[4];
#pragma unroll
  for (int j = 0; j < 4; j++) v[j] = (base + j < n) ? deg[base + j] : 0;
  const int tsum = v[0] + v[1] + v[2] + v[3];
  sh[t] = tsum;
  __syncthreads();
  for (int off = 1; off < 256; off <<= 1) {
    int x = (t >= off) ? sh[t - off] : 0;
    __syncthreads();
    sh[t] += x;
    __syncthreads();
  }
  if (t == 255) partials[blockIdx.x] = sh[255];
  int run = sh[t] - tsum;
#pragma unroll
  for (int j = 0; j < 4; j++) {
    if (base + j < n) offs[base + j] = run;
    run += v[j];
  }
}

__global__ void scan2(int* __restrict__ partials, int nb) {
  if (threadIdx.x == 0 && blockIdx.x == 0) {
    int run = 0;
    for (int i = 0; i < nb; i++) {
      int t = partials[i];
      partials[i] = run;
      run += t;
    }
  }
}

__global__ __launch_bounds__(256) void scan3(int* __restrict__ offs,
                                             const int* __restrict__ partials,
                                             int* __restrict__ cur, int n, int total) {
  const int t = threadIdx.x;
  const int base = blockIdx.x * 1024 + t * 4;
  const int add = partials[blockIdx.x];
#pragma unroll
  for (int j = 0; j < 4; j++) {
    const int i = base + j;
    if (i < n) {
      const int v = offs[i] + add;
      offs[i] = v;
      cur[i] = v;
    }
  }
  if (blockIdx.x == 0 && t == 0) offs[n] = total;
}

// Packed (col, ew) scatter: ONE 8B store per edge instead of two 4B stores to
// two separate arrays. Halves the number of distinct dirty-line touches, so the
// scattered-write HBM amplification (145 MB measured vs 12.8 MB ideal) ~halves.
__global__ __launch_bounds__(256) void bucket_edges(
    const int* __restrict__ row, const int* __restrict__ col, const float* __restrict__ ew,
    int* __restrict__ cur, int2* __restrict__ sedge, int E) {
  int e = blockIdx.x * 256 + threadIdx.x;
  if (e >= E) return;
  const int r = row[e];
  const int pos = atomicAdd(&cur[r], 1);
  sedge[pos] = make_int2(col[e], __float_as_int(ew[e]));
}

// ------- fused aggregate (bf16 hp gather) + residual + LayerNorm, 1 wave/row -------
__global__ __launch_bounds__(256) void agg_ln(
    const u16* __restrict__ hpb, const int* __restrict__ offs,
    const int2* __restrict__ sedge,
    const float* __restrict__ res, const float* __restrict__ g, const float* __restrict__ b,
    float* __restrict__ out, int nrows) {
  const int wave = threadIdx.x >> 6;
  const int lane = threadIdx.x & 63;
  const int r = blockIdx.x * 4 + wave;
  if (r >= nrows) return;
  const int f4 = lane * 4;

  float4 acc = *(const float4*)(res + (size_t)r * 256 + f4);
  int k = offs[r];
  const int kend = offs[r + 1];
  for (; k + 3 < kend; k += 4) {
    const int2 e0 = sedge[k], e1 = sedge[k + 1], e2 = sedge[k + 2], e3 = sedge[k + 3];
    const float w0 = __int_as_float(e0.y), w1 = __int_as_float(e1.y);
    const float w2 = __int_as_float(e2.y), w3 = __int_as_float(e3.y);
    const ushort4 h0 = *(const ushort4*)(hpb + (size_t)e0.x * 256 + f4);
    const ushort4 h1 = *(const ushort4*)(hpb + (size_t)e1.x * 256 + f4);
    const ushort4 h2 = *(const ushort4*)(hpb + (size_t)e2.x * 256 + f4);
    const ushort4 h3 = *(const ushort4*)(hpb + (size_t)e3.x * 256 + f4);
    acc.x += w0 * b2f(h0.x) + w1 * b2f(h1.x) + w2 * b2f(h2.x) + w3 * b2f(h3.x);
    acc.y += w0 * b2f(h0.y) + w1 * b2f(h1.y) + w2 * b2f(h2.y) + w3 * b2f(h3.y);
    acc.z += w0 * b2f(h0.z) + w1 * b2f(h1.z) + w2 * b2f(h2.z) + w3 * b2f(h3.z);
    acc.w += w0 * b2f(h0.w) + w1 * b2f(h1.w) + w2 * b2f(h2.w) + w3 * b2f(h3.w);
  }
  for (; k < kend; ++k) {
    const int2 e = sedge[k];
    const float w = __int_as_float(e.y);
    const ushort4 h = *(const ushort4*)(hpb + (size_t)e.x * 256 + f4);
    acc.x += w * b2f(h.x); acc.y += w * b2f(h.y);
    acc.z += w * b2f(h.z); acc.w += w * b2f(h.w);
  }

  float s = acc.x + acc.y + acc.z + acc.w;
#pragma unroll
  for (int m = 32; m >= 1; m >>= 1) s += __shfl_xor(s, m);
  const float mu = s * (1.f / 256.f);
  acc.x -= mu; acc.y -= mu; acc.z -= mu; acc.w -= mu;
  float ss = acc.x * acc.x + acc.y * acc.y + acc.z * acc.z + acc.w * acc.w;
#pragma unroll
  for (int m = 32; m >= 1; m >>= 1) ss += __shfl_xor(ss, m);
  const float rs = rsqrtf(ss * (1.f / 256.f) + 1e-5f);

  const float4 gg = *(const float4*)(g + f4);
  const float4 bb = *(const float4*)(b + f4);
  float4 o;
  o.x = acc.x * rs * gg.x + bb.x;
  o.y = acc.y * rs * gg.y + bb.y;
  o.z = acc.z * rs * gg.z + bb.z;
  o.w = acc.w * rs * gg.w + bb.w;
  *(float4*)(out + (size_t)r * 256 + f4) = o;
}

extern "C" void kernel_launch(void* const* d_in, const int* in_sizes, int n_in,
                              void* d_out, int out_size, void* d_ws, size_t ws_size,
                              hipStream_t stream) {
  const float* x0    = (const float*)d_in[0];
  const float* x1    = (const float*)d_in[1];
  const float* W0    = (const float*)d_in[2];
  const float* W1    = (const float*)d_in[3];
  const float* Wres1 = (const float*)d_in[4];
  const float* g0    = (const float*)d_in[5];
  const float* b0    = (const float*)d_in[6];
  const float* g1    = (const float*)d_in[7];
  const float* b1    = (const float*)d_in[8];
  const float* ew0   = (const float*)d_in[9];
  const float* ew1   = (const float*)d_in[10];
  const int*   row0  = (const int*)d_in[11];
  const int*   col0  = (const int*)d_in[12];
  const int*   row1  = (const int*)d_in[13];
  const int*   col1  = (const int*)d_in[14];
  float* out = (float*)d_out;

  const int N = 50000, D0 = 256, D1 = 512, DO = 256, E = 1600000;
  const int NB = (N + 1023) / 1024;

  // ws layout (bytes, 16B-aligned)
  char* w = (char*)d_ws;
  u16*   hpb   = (u16*)  (w);                  // 25,600,000
  u16*   wtb   = (u16*)  (w + 25600000);       //    262,144 (max 512x256 bf16)
  int2*  sedge = (int2*) (w + 25862144);       // 12,800,000 (packed col+ew)
  int*   offs  = (int*)  (w + 38662144);       //    200,004 (N+1)
  int*   cur   = (int*)  (w + 38862208);       //    200,000
  int*   deg   = (int*)  (w + 39062208);       //    200,000
  int*   parts = (int*)  (w + 39262208);       //        196

  float* out0 = out;
  float* out1 = out + (size_t)N * DO;

  const dim3 blk(256);
  const dim3 gemm_grid(2, (N + 127) / 128);
  const dim3 edge_grid((E + 255) / 256);
  const dim3 row_grid((N + 255) / 256);
  const dim3 agg_grid((N + 3) / 4);

  auto build_csr = [&](const int* row, const int* col, const float* ew) {
    zero_i32<<<row_grid, blk, 0, stream>>>(deg, N);
    hist_rows<<<edge_grid, blk, 0, stream>>>(row, deg, E);
    scan1<<<dim3(NB), blk, 0, stream>>>(deg, offs, parts, N);
    scan2<<<dim3(1), dim3(64), 0, stream>>>(parts, NB);
    scan3<<<dim3(NB), blk, 0, stream>>>(offs, parts, cur, N, E);
    bucket_edges<<<edge_grid, blk, 0, stream>>>(row, col, ew, cur, sedge, E);
  };

  // ---- type 0: identity residual ----
  build_csr(row0, col0, ew0);
  conv_wt<<<dim3(D0), blk, 0, stream>>>(W0, wtb, D0);
  gemm_bf16<true><<<gemm_grid, blk, 0, stream>>>(x0, wtb, hpb, N, D0);
  agg_ln<<<agg_grid, blk, 0, stream>>>(hpb, offs, sedge, x0, g0, b0, out0, N);

  // ---- type 1: projected residual ----
  conv_wt<<<dim3(D1), blk, 0, stream>>>(Wres1, wtb, D1);
  gemm_bf16<false><<<gemm_grid, blk, 0, stream>>>(x1, wtb, out1, N, D1);
  build_csr(row1, col1, ew1);
  conv_wt<<<dim3(D1), blk, 0, stream>>>(W1, wtb, D1);
  gemm_bf16<true><<<gemm_grid, blk, 0, stream>>>(x1, wtb, hpb, N, D1);
  agg_ln<<<agg_grid, blk, 0, stream>>>(hpb, offs, sedge, out1, g1, b1, out1, N);
}

// Round 2
// 737.608 us; speedup vs baseline: 1.3379x; 1.3379x over previous
//
#include <hip/hip_runtime.h>
#include <hip/hip_bf16.h>
#include <cstddef>

typedef unsigned short u16;
typedef u16 u16x8 __attribute__((ext_vector_type(8)));
typedef __bf16 bf16x8 __attribute__((ext_vector_type(8)));
typedef float f32x4 __attribute__((ext_vector_type(4)));

__device__ __forceinline__ u16 f2b(float f) {
  unsigned int u = __float_as_uint(f);
  unsigned int r = 0x7FFFu + ((u >> 16) & 1u);
  return (u16)((u + r) >> 16);
}
__device__ __forceinline__ float b2f(u16 u) {
  return __uint_as_float(((unsigned int)u) << 16);
}

// ---------------- bf16 MFMA GEMM: C[M,256] = A[M,K](fp32) @ Wt[256,K](bf16)^T --------
// 128x128 tile, 256 threads = 4 waves in 2x2 quadrants of 64x64.
// A conversion fp32->bf16 fused into LDS staging. XOR-swizzled LDS (c ^= row&7)
// keeps ds_read_b128 at the 8-cycle floor.
template <bool OUT_BF16>
__global__ __launch_bounds__(256) void gemm_bf16(
    const float* __restrict__ A, const u16* __restrict__ Bt, void* __restrict__ Cv,
    int M, int K) {
  __shared__ u16 As[128 * 64];
  __shared__ u16 Bs[128 * 64];
  const int tid = threadIdx.x;
  const int wid = tid >> 6;
  const int lane = tid & 63;
  const int brow = blockIdx.y * 128;
  const int bcol = blockIdx.x * 128;
  const int waveM = (wid >> 1) * 64;
  const int waveN = (wid & 1) * 64;
  const int q = lane >> 4;
  const int rl = lane & 15;

  f32x4 acc[4][4] = {};

  const int arow = tid >> 1;         // 0..127
  const int khalf = (tid & 1) * 32;  // element offset within 64-chunk
  const int garow = brow + arow;
  const bool aok = garow < M;
  const int swz = arow & 7;

  for (int k0 = 0; k0 < K; k0 += 64) {
    {  // stage A (fp32 -> bf16)
      const float* src = A + (size_t)garow * K + k0 + khalf;
      u16* dstrow = As + arow * 64;
#pragma unroll
      for (int j = 0; j < 4; ++j) {
        float4 v0 = make_float4(0.f, 0.f, 0.f, 0.f), v1 = v0;
        if (aok) {
          v0 = *(const float4*)(src + j * 8);
          v1 = *(const float4*)(src + j * 8 + 4);
        }
        u16x8 v = {f2b(v0.x), f2b(v0.y), f2b(v0.z), f2b(v0.w),
                   f2b(v1.x), f2b(v1.y), f2b(v1.z), f2b(v1.w)};
        const int c = (khalf >> 3) + j;
        *(u16x8*)(dstrow + 8 * (c ^ swz)) = v;
      }
    }
    {  // stage Bt (already bf16); Bt row = bcol + arow, always < 256
      const u16* src = Bt + (size_t)(bcol + arow) * K + k0 + khalf;
      u16* dstrow = Bs + arow * 64;
#pragma unroll
      for (int j = 0; j < 4; ++j) {
        u16x8 v = *(const u16x8*)(src + j * 8);
        const int c = (khalf >> 3) + j;
        *(u16x8*)(dstrow + 8 * (c ^ swz)) = v;
      }
    }
    __syncthreads();
#pragma unroll
    for (int ks = 0; ks < 2; ++ks) {
      bf16x8 af[4], bfr[4];
      const int cbase = ks * 4 + q;
#pragma unroll
      for (int i = 0; i < 4; ++i) {
        const int r = waveM + 16 * i + rl;
        af[i] = __builtin_bit_cast(bf16x8,
                 *(const u16x8*)(As + r * 64 + 8 * (cbase ^ (rl & 7))));
      }
#pragma unroll
      for (int j = 0; j < 4; ++j) {
        const int r = waveN + 16 * j + rl;
        bfr[j] = __builtin_bit_cast(bf16x8,
                  *(const u16x8*)(Bs + r * 64 + 8 * (cbase ^ (rl & 7))));
      }
#pragma unroll
      for (int i = 0; i < 4; ++i)
#pragma unroll
        for (int j = 0; j < 4; ++j)
          acc[i][j] = __builtin_amdgcn_mfma_f32_16x16x32_bf16(af[i], bfr[j], acc[i][j], 0, 0, 0);
    }
    __syncthreads();
  }

  // epilogue: C/D layout col=lane&15, row=quad*4+reg (m89/m91-verified)
#pragma unroll
  for (int i = 0; i < 4; ++i) {
#pragma unroll
    for (int reg = 0; reg < 4; ++reg) {
      const int gr = brow + waveM + 16 * i + q * 4 + reg;
      if (gr >= M) continue;
#pragma unroll
      for (int j = 0; j < 4; ++j) {
        const int col = bcol + waveN + 16 * j + rl;
        const float v = acc[i][j][reg];
        if (OUT_BF16) ((u16*)Cv)[(size_t)gr * 256 + col] = f2b(v);
        else          ((float*)Cv)[(size_t)gr * 256 + col] = v;
      }
    }
  }
}

// ---------------- W[K][256] fp32 -> Wt[256][K] bf16 ----------------
__global__ __launch_bounds__(256) void conv_wt(const float* __restrict__ W,
                                               u16* __restrict__ Wt, int K) {
  const int idx = blockIdx.x * 256 + threadIdx.x;  // over K*256
  const int k = idx >> 8;
  const int n = idx & 255;
  if (k < K) Wt[(size_t)n * K + k] = f2b(W[idx]);
}

// ---------------- CSR build: two-level counting bucket sort, LDS atomics only -------
// Coarse bucket = row>>7 (128 rows/bucket). NBUK buckets, EB edge-chunks.
// pa_hist -> scan(ghist) -> pa_scatter(tmp, bucket-grouped) -> pb_sort(CSR + offs).
// Replaces hist_rows + bucket_edges (2x1.6M global atomic-returns @ ~12.6 G/s,
// ~480 us total) with LDS-atomic ranking.
#define EB   256   // edge chunks (blocks) for pass A
#define RPB  128   // rows per coarse bucket
#define NBUK 391   // ceil(50048/128); covers rows 0..50047 for N=50000

__global__ __launch_bounds__(256) void pa_hist(const int* __restrict__ row,
                                               int* __restrict__ ghist, int E) {
  __shared__ int h[NBUK];
  for (int i = threadIdx.x; i < NBUK; i += 256) h[i] = 0;
  __syncthreads();
  const int per = (E + EB - 1) / EB;
  const int s = blockIdx.x * per;
  const int e = min(E, s + per);
  for (int i = s + threadIdx.x; i < e; i += 256) atomicAdd(&h[row[i] >> 7], 1);
  __syncthreads();
  for (int i = threadIdx.x; i < NBUK; i += 256) ghist[i * EB + blockIdx.x] = h[i];
}

__global__ __launch_bounds__(256) void pa_scatter(
    const int* __restrict__ row, const int* __restrict__ col, const float* __restrict__ ew,
    const int* __restrict__ gscan, int2* __restrict__ tmp, int E) {
  __shared__ int cur[NBUK];
  for (int i = threadIdx.x; i < NBUK; i += 256) cur[i] = gscan[i * EB + blockIdx.x];
  __syncthreads();
  const int per = (E + EB - 1) / EB;
  const int s = blockIdx.x * per;
  const int e = min(E, s + per);
  // 4-way unroll: 4 independent load chains in flight per thread (only 1 block/CU).
  for (int i0 = s + threadIdx.x; i0 < e; i0 += 1024) {
    int r[4], c[4], wv[4];
    bool ok[4];
#pragma unroll
    for (int j = 0; j < 4; ++j) {
      const int i = i0 + j * 256;
      ok[j] = i < e;
      if (ok[j]) { r[j] = row[i]; c[j] = col[i]; wv[j] = __float_as_int(ew[i]); }
    }
#pragma unroll
    for (int j = 0; j < 4; ++j)
      if (ok[j]) {
        const int pos = atomicAdd(&cur[r[j] >> 7], 1);
        tmp[pos] = make_int2(((r[j] & 127) << 16) | c[j], wv[j]);  // col < 65536
      }
  }
}

__global__ __launch_bounds__(256) void pb_sort(
    const int2* __restrict__ tmp, const int* __restrict__ gscan,
    int2* __restrict__ sedge, int* __restrict__ offs, int E, int N) {
  __shared__ int h[RPB];
  __shared__ int ex[RPB];
  __shared__ int cur[RPB];
  const int b = blockIdx.x;
  const int t = threadIdx.x;
  const int base = gscan[b * EB];
  const int end = (b == NBUK - 1) ? E : gscan[(b + 1) * EB];
  if (t < RPB) h[t] = 0;
  __syncthreads();
  for (int i = base + t; i < end; i += 256) atomicAdd(&h[(tmp[i].x >> 16) & 127], 1);
  __syncthreads();
  if (t == 0) {
    int run = base;
    for (int r = 0; r < RPB; ++r) { const int cc = h[r]; ex[r] = run; cur[r] = run; run += cc; }
  }
  __syncthreads();
  if (t < RPB) {
    const int rg = b * RPB + t;
    if (rg <= N) offs[rg] = ex[t];   // rg==N lands exactly at E (all edges below it)
  }
  for (int i = base + t; i < end; i += 256) {
    const int2 v = tmp[i];
    const int pos = atomicAdd(&cur[(v.x >> 16) & 127], 1);
    sedge[pos] = make_int2(v.x & 0xFFFF, v.y);
  }
}

// ---------------- scan helpers (reused) ----------------
__global__ __launch_bounds__(256) void scan1(const int* __restrict__ deg,
                                             int* __restrict__ offs,
                                             int* __restrict__ partials, int n) {
  __shared__ int sh[256];
  const int t = threadIdx.x;
  const int base = blockIdx.x * 1024 + t * 4;
  int v[4];
#pragma unroll
  for (int j = 0; j < 4; j++) v[j] = (base + j < n) ? deg[base + j] : 0;
  const int tsum = v[0] + v[1] + v[2] + v[3];
  sh[t] = tsum;
  __syncthreads();
  for (int off = 1; off < 256; off <<= 1) {
    int x = (t >= off) ? sh[t - off] : 0;
    __syncthreads();
    sh[t] += x;
    __syncthreads();
  }
  if (t == 255) partials[blockIdx.x] = sh[255];
  int run = sh[t] - tsum;
#pragma unroll
  for (int j = 0; j < 4; j++) {
    if (base + j < n) offs[base + j] = run;
    run += v[j];
  }
}

__global__ void scan2(int* __restrict__ partials, int nb) {
  if (threadIdx.x == 0 && blockIdx.x == 0) {
    int run = 0;
    for (int i = 0; i < nb; i++) {
      int t = partials[i];
      partials[i] = run;
      run += t;
    }
  }
}

__global__ __launch_bounds__(256) void scan_add(int* __restrict__ a,
                                                const int* __restrict__ partials, int n) {
  const int t = threadIdx.x;
  const int base = blockIdx.x * 1024 + t * 4;
  const int add = partials[blockIdx.x];
#pragma unroll
  for (int j = 0; j < 4; j++)
    if (base + j < n) a[base + j] += add;
}

// ------- fused aggregate (bf16 hp gather) + residual + LayerNorm, 1 wave/row -------
__global__ __launch_bounds__(256) void agg_ln(
    const u16* __restrict__ hpb, const int* __restrict__ offs,
    const int2* __restrict__ sedge,
    const float* __restrict__ res, const float* __restrict__ g, const float* __restrict__ b,
    float* __restrict__ out, int nrows) {
  const int wave = threadIdx.x >> 6;
  const int lane = threadIdx.x & 63;
  const int r = blockIdx.x * 4 + wave;
  if (r >= nrows) return;
  const int f4 = lane * 4;

  float4 acc = *(const float4*)(res + (size_t)r * 256 + f4);
  int k = offs[r];
  const int kend = offs[r + 1];
  for (; k + 3 < kend; k += 4) {
    const int2 e0 = sedge[k], e1 = sedge[k + 1], e2 = sedge[k + 2], e3 = sedge[k + 3];
    const float w0 = __int_as_float(e0.y), w1 = __int_as_float(e1.y);
    const float w2 = __int_as_float(e2.y), w3 = __int_as_float(e3.y);
    const ushort4 h0 = *(const ushort4*)(hpb + (size_t)e0.x * 256 + f4);
    const ushort4 h1 = *(const ushort4*)(hpb + (size_t)e1.x * 256 + f4);
    const ushort4 h2 = *(const ushort4*)(hpb + (size_t)e2.x * 256 + f4);
    const ushort4 h3 = *(const ushort4*)(hpb + (size_t)e3.x * 256 + f4);
    acc.x += w0 * b2f(h0.x) + w1 * b2f(h1.x) + w2 * b2f(h2.x) + w3 * b2f(h3.x);
    acc.y += w0 * b2f(h0.y) + w1 * b2f(h1.y) + w2 * b2f(h2.y) + w3 * b2f(h3.y);
    acc.z += w0 * b2f(h0.z) + w1 * b2f(h1.z) + w2 * b2f(h2.z) + w3 * b2f(h3.z);
    acc.w += w0 * b2f(h0.w) + w1 * b2f(h1.w) + w2 * b2f(h2.w) + w3 * b2f(h3.w);
  }
  for (; k < kend; ++k) {
    const int2 e = sedge[k];
    const float w = __int_as_float(e.y);
    const ushort4 h = *(const ushort4*)(hpb + (size_t)e.x * 256 + f4);
    acc.x += w * b2f(h.x); acc.y += w * b2f(h.y);
    acc.z += w * b2f(h.z); acc.w += w * b2f(h.w);
  }

  float s = acc.x + acc.y + acc.z + acc.w;
#pragma unroll
  for (int m = 32; m >= 1; m >>= 1) s += __shfl_xor(s, m);
  const float mu = s * (1.f / 256.f);
  acc.x -= mu; acc.y -= mu; acc.z -= mu; acc.w -= mu;
  float ss = acc.x * acc.x + acc.y * acc.y + acc.z * acc.z + acc.w * acc.w;
#pragma unroll
  for (int m = 32; m >= 1; m >>= 1) ss += __shfl_xor(ss, m);
  const float rs = rsqrtf(ss * (1.f / 256.f) + 1e-5f);

  const float4 gg = *(const float4*)(g + f4);
  const float4 bb = *(const float4*)(b + f4);
  float4 o;
  o.x = acc.x * rs * gg.x + bb.x;
  o.y = acc.y * rs * gg.y + bb.y;
  o.z = acc.z * rs * gg.z + bb.z;
  o.w = acc.w * rs * gg.w + bb.w;
  *(float4*)(out + (size_t)r * 256 + f4) = o;
}

extern "C" void kernel_launch(void* const* d_in, const int* in_sizes, int n_in,
                              void* d_out, int out_size, void* d_ws, size_t ws_size,
                              hipStream_t stream) {
  const float* x0    = (const float*)d_in[0];
  const float* x1    = (const float*)d_in[1];
  const float* W0    = (const float*)d_in[2];
  const float* W1    = (const float*)d_in[3];
  const float* Wres1 = (const float*)d_in[4];
  const float* g0    = (const float*)d_in[5];
  const float* b0    = (const float*)d_in[6];
  const float* g1    = (const float*)d_in[7];
  const float* b1    = (const float*)d_in[8];
  const float* ew0   = (const float*)d_in[9];
  const float* ew1   = (const float*)d_in[10];
  const int*   row0  = (const int*)d_in[11];
  const int*   col0  = (const int*)d_in[12];
  const int*   row1  = (const int*)d_in[13];
  const int*   col1  = (const int*)d_in[14];
  float* out = (float*)d_out;

  const int N = 50000, D0 = 256, D1 = 512, DO = 256, E = 1600000;

  // ws layout (bytes, 16B-aligned) — stays within the proven ~39.26 MB footprint.
  char* w = (char*)d_ws;
  u16*   hpb   = (u16*)  (w);                  // 25,600,000
  u16*   wtb   = (u16*)  (w + 25600000);       //    262,144 (max 512x256 bf16)
  int2*  sedge = (int2*) (w + 25862144);       // 12,800,000 (packed col+ew, CSR order)
  int*   offs  = (int*)  (w + 38662144);       //    200,004 (N+1)
  int*   ghist = (int*)  (w + 38862160);       //    400,384 (NBUK*EB ints)
  int*   parts = (int*)  (w + 39262560);       //        392 (scan partials)
  // tmp (bucket-grouped edges) aliases hpb: hpb is dead during both CSR builds
  // (type0: built before gemm fills hpb; type1: built between out1-gemm and hpb-gemm).
  int2*  tmp   = (int2*) (w);                  // 12,800,000 (aliases hpb)

  float* out0 = out;
  float* out1 = out + (size_t)N * DO;

  const dim3 blk(256);
  const dim3 gemm_grid(2, (N + 127) / 128);
  const dim3 agg_grid((N + 3) / 4);
  const int NGH = NBUK * EB;                 // 100,096
  const int NBS = (NGH + 1023) / 1024;       // 98

  auto build_csr = [&](const int* row, const int* col, const float* ew) {
    pa_hist<<<dim3(EB), blk, 0, stream>>>(row, ghist, E);
    scan1<<<dim3(NBS), blk, 0, stream>>>(ghist, ghist, parts, NGH);
    scan2<<<dim3(1), dim3(64), 0, stream>>>(parts, NBS);
    scan_add<<<dim3(NBS), blk, 0, stream>>>(ghist, parts, NGH);
    pa_scatter<<<dim3(EB), blk, 0, stream>>>(row, col, ew, ghist, tmp, E);
    pb_sort<<<dim3(NBUK), blk, 0, stream>>>(tmp, ghist, sedge, offs, E, N);
  };

  // ---- type 0: identity residual ----
  build_csr(row0, col0, ew0);
  conv_wt<<<dim3(D0), blk, 0, stream>>>(W0, wtb, D0);
  gemm_bf16<true><<<gemm_grid, blk, 0, stream>>>(x0, wtb, hpb, N, D0);
  agg_ln<<<agg_grid, blk, 0, stream>>>(hpb, offs, sedge, x0, g0, b0, out0, N);

  // ---- type 1: projected residual ----
  conv_wt<<<dim3(D1), blk, 0, stream>>>(Wres1, wtb, D1);
  gemm_bf16<false><<<gemm_grid, blk, 0, stream>>>(x1, wtb, out1, N, D1);
  build_csr(row1, col1, ew1);
  conv_wt<<<dim3(D1), blk, 0, stream>>>(W1, wtb, D1);
  gemm_bf16<true><<<gemm_grid, blk, 0, stream>>>(x1, wtb, hpb, N, D1);
  agg_ln<<<agg_grid, blk, 0, stream>>>(hpb, offs, sedge, out1, g1, b1, out1, N);
}

// Round 4
// 707.377 us; speedup vs baseline: 1.3950x; 1.0427x over previous
//
#include <hip/hip_runtime.h>
#include <hip/hip_bf16.h>
#include <cstddef>

typedef unsigned short u16;
typedef u16 u16x8 __attribute__((ext_vector_type(8)));
typedef __bf16 bf16x8 __attribute__((ext_vector_type(8)));
typedef float f32x4 __attribute__((ext_vector_type(4)));

__device__ __forceinline__ u16 f2b(float f) {
  unsigned int u = __float_as_uint(f);
  unsigned int r = 0x7FFFu + ((u >> 16) & 1u);
  return (u16)((u + r) >> 16);
}
__device__ __forceinline__ float b2f(u16 u) {
  return __uint_as_float(((unsigned int)u) << 16);
}

// ---------------- bf16 MFMA GEMM: C[M,256] = A[M,K](fp32) @ Wt[256,K](bf16)^T --------
// BM=64 x BN=256 tile (full output width per block): each A-tile staged ONCE,
// halving A HBM reads vs the previous BN=128 variant. 256 threads = 4 waves,
// wave w owns rows 0..63 x cols [64w, 64w+64). LDS 40 KB -> 4 blocks/CU.
// XOR-swizzled LDS (c ^= row&7) keeps ds_read_b128 conflict-free.
template <bool OUT_BF16>
__global__ __launch_bounds__(256) void gemm_bf16(
    const float* __restrict__ A, const u16* __restrict__ Bt, void* __restrict__ Cv,
    int M, int K) {
  __shared__ u16 As[64 * 64];
  __shared__ u16 Bs[256 * 64];
  const int tid = threadIdx.x;
  const int wid = tid >> 6;
  const int lane = tid & 63;
  const int brow = blockIdx.x * 64;
  const int waveN = wid * 64;
  const int q = lane >> 4;
  const int rl = lane & 15;

  f32x4 acc[4][4] = {};

  // A staging: 64 rows x 64 cols fp32->bf16; 4 threads/row, 16 cols each.
  const int arow = tid >> 2;         // 0..63
  const int kq = (tid & 3) * 16;     // 0,16,32,48
  const int garow = brow + arow;
  const bool aok = garow < M;
  const int aswz = arow & 7;
  // B staging: 256 rows x 64 cols bf16; 1 thread/row.
  const int brb = tid;               // 0..255
  const int bswz = brb & 7;

  for (int k0 = 0; k0 < K; k0 += 64) {
    {  // stage A (fp32 -> bf16)
      const float* src = A + (size_t)garow * K + k0 + kq;
      u16* dstrow = As + arow * 64;
#pragma unroll
      for (int j = 0; j < 2; ++j) {
        float4 v0 = make_float4(0.f, 0.f, 0.f, 0.f), v1 = v0;
        if (aok) {
          v0 = *(const float4*)(src + j * 8);
          v1 = *(const float4*)(src + j * 8 + 4);
        }
        u16x8 v = {f2b(v0.x), f2b(v0.y), f2b(v0.z), f2b(v0.w),
                   f2b(v1.x), f2b(v1.y), f2b(v1.z), f2b(v1.w)};
        const int c = (kq >> 3) + j;
        *(u16x8*)(dstrow + 8 * (c ^ aswz)) = v;
      }
    }
    {  // stage Bt (already bf16): full 128 B row per thread
      const u16* src = Bt + (size_t)brb * K + k0;
      u16* dstrow = Bs + brb * 64;
#pragma unroll
      for (int j = 0; j < 8; ++j) {
        u16x8 v = *(const u16x8*)(src + j * 8);
        *(u16x8*)(dstrow + 8 * (j ^ bswz)) = v;
      }
    }
    __syncthreads();
#pragma unroll
    for (int ks = 0; ks < 2; ++ks) {
      bf16x8 af[4], bfr[4];
      const int cbase = ks * 4 + q;
#pragma unroll
      for (int i = 0; i < 4; ++i) {
        const int r = 16 * i + rl;
        af[i] = __builtin_bit_cast(bf16x8,
                 *(const u16x8*)(As + r * 64 + 8 * (cbase ^ (rl & 7))));
      }
#pragma unroll
      for (int j = 0; j < 4; ++j) {
        const int r = waveN + 16 * j + rl;
        bfr[j] = __builtin_bit_cast(bf16x8,
                  *(const u16x8*)(Bs + r * 64 + 8 * (cbase ^ (rl & 7))));
      }
#pragma unroll
      for (int i = 0; i < 4; ++i)
#pragma unroll
        for (int j = 0; j < 4; ++j)
          acc[i][j] = __builtin_amdgcn_mfma_f32_16x16x32_bf16(af[i], bfr[j], acc[i][j], 0, 0, 0);
    }
    __syncthreads();
  }

  // epilogue: C/D layout col=lane&15, row=quad*4+reg (m89/m91-verified)
#pragma unroll
  for (int i = 0; i < 4; ++i) {
#pragma unroll
    for (int reg = 0; reg < 4; ++reg) {
      const int gr = brow + 16 * i + q * 4 + reg;
      if (gr >= M) continue;
#pragma unroll
      for (int j = 0; j < 4; ++j) {
        const int col = waveN + 16 * j + rl;
        const float v = acc[i][j][reg];
        if (OUT_BF16) ((u16*)Cv)[(size_t)gr * 256 + col] = f2b(v);
        else          ((float*)Cv)[(size_t)gr * 256 + col] = v;
      }
    }
  }
}

// ---------------- W[K][256] fp32 -> Wt[256][K] bf16 ----------------
__global__ __launch_bounds__(256) void conv_wt(const float* __restrict__ W,
                                               u16* __restrict__ Wt, int K) {
  const int idx = blockIdx.x * 256 + threadIdx.x;  // over K*256
  const int k = idx >> 8;
  const int n = idx & 255;
  if (k < K) Wt[(size_t)n * K + k] = f2b(W[idx]);
}

// ---------------- CSR build: two-level counting bucket sort, LDS atomics only -------
#define EB   256   // edge chunks (blocks) for pass A
#define RPB  128   // rows per coarse bucket
#define NBUK 391   // ceil(50048/128); covers rows 0..50047 for N=50000

__global__ __launch_bounds__(256) void pa_hist(const int* __restrict__ row,
                                               int* __restrict__ ghist, int E) {
  __shared__ int h[NBUK];
  for (int i = threadIdx.x; i < NBUK; i += 256) h[i] = 0;
  __syncthreads();
  const int per = (E + EB - 1) / EB;
  const int s = blockIdx.x * per;
  const int e = min(E, s + per);
  for (int i = s + threadIdx.x; i < e; i += 256) atomicAdd(&h[row[i] >> 7], 1);
  __syncthreads();
  for (int i = threadIdx.x; i < NBUK; i += 256) ghist[i * EB + blockIdx.x] = h[i];
}

__global__ __launch_bounds__(256) void pa_scatter(
    const int* __restrict__ row, const int* __restrict__ col, const float* __restrict__ ew,
    const int* __restrict__ gscan, int2* __restrict__ tmp, int E) {
  __shared__ int cur[NBUK];
  for (int i = threadIdx.x; i < NBUK; i += 256) cur[i] = gscan[i * EB + blockIdx.x];
  __syncthreads();
  const int per = (E + EB - 1) / EB;
  const int s = blockIdx.x * per;
  const int e = min(E, s + per);
  for (int i0 = s + threadIdx.x; i0 < e; i0 += 1024) {
    int r[4], c[4], wv[4];
    bool ok[4];
#pragma unroll
    for (int j = 0; j < 4; ++j) {
      const int i = i0 + j * 256;
      ok[j] = i < e;
      if (ok[j]) { r[j] = row[i]; c[j] = col[i]; wv[j] = __float_as_int(ew[i]); }
    }
#pragma unroll
    for (int j = 0; j < 4; ++j)
      if (ok[j]) {
        const int pos = atomicAdd(&cur[r[j] >> 7], 1);
        tmp[pos] = make_int2(((r[j] & 127) << 16) | c[j], wv[j]);  // col < 65536
      }
  }
}

__global__ __launch_bounds__(256) void pb_sort(
    const int2* __restrict__ tmp, const int* __restrict__ gscan,
    int2* __restrict__ sedge, int* __restrict__ offs, int E, int N) {
  __shared__ int h[RPB];
  __shared__ int ex[RPB];
  __shared__ int cur[RPB];
  const int b = blockIdx.x;
  const int t = threadIdx.x;
  const int base = gscan[b * EB];
  const int end = (b == NBUK - 1) ? E : gscan[(b + 1) * EB];
  if (t < RPB) h[t] = 0;
  __syncthreads();
  for (int i = base + t; i < end; i += 256) atomicAdd(&h[(tmp[i].x >> 16) & 127], 1);
  __syncthreads();
  if (t == 0) {
    int run = base;
    for (int r = 0; r < RPB; ++r) { const int cc = h[r]; ex[r] = run; cur[r] = run; run += cc; }
  }
  __syncthreads();
  if (t < RPB) {
    const int rg = b * RPB + t;
    if (rg <= N) offs[rg] = ex[t];
  }
  for (int i = base + t; i < end; i += 256) {
    const int2 v = tmp[i];
    const int pos = atomicAdd(&cur[(v.x >> 16) & 127], 1);
    sedge[pos] = make_int2(v.x & 0xFFFF, v.y);
  }
}

// ---------------- scan helpers ----------------
__global__ __launch_bounds__(256) void scan1(const int* __restrict__ deg,
                                             int* __restrict__ offs,
                                             int* __restrict__ partials, int n) {
  __shared__ int sh[256];
  const int t = threadIdx.x;
  const int base = blockIdx.x * 1024 + t * 4;
  int v[4];
#pragma unroll
  for (int j = 0; j < 4; j++) v[j] = (base + j < n) ? deg[base + j] : 0;
  const int tsum = v[0] + v[1] + v[2] + v[3];
  sh[t] = tsum;
  __syncthreads();
  for (int off = 1; off < 256; off <<= 1) {
    int x = (t >= off) ? sh[t - off] : 0;
    __syncthreads();
    sh[t] += x;
    __syncthreads();
  }
  if (t == 255) partials[blockIdx.x] = sh[255];
  int run = sh[t] - tsum;
#pragma unroll
  for (int j = 0; j < 4; j++) {
    if (base + j < n) offs[base + j] = run;
    run += v[j];
  }
}

__global__ void scan2(int* __restrict__ partials, int nb) {
  if (threadIdx.x == 0 && blockIdx.x == 0) {
    int run = 0;
    for (int i = 0; i < nb; i++) {
      int t = partials[i];
      partials[i] = run;
      run += t;
    }
  }
}

__global__ __launch_bounds__(256) void scan_add(int* __restrict__ a,
                                                const int* __restrict__ partials, int n) {
  const int t = threadIdx.x;
  const int base = blockIdx.x * 1024 + t * 4;
  const int add = partials[blockIdx.x];
#pragma unroll
  for (int j = 0; j < 4; j++)
    if (base + j < n) a[base + j] += add;
}

// ------- fused aggregate (bf16 hp gather) + residual + LayerNorm, 1 wave/row -------
// Wave split into two 32-lane halves; each half owns alternating edges with
// 16 B/lane (u16x8) gathers -> 1 KB per gather instr, half the vmem instrs/edge,
// 8 edges in flight per wave. Halves combined via shfl_xor(32); both halves then
// hold duplicated sums, so LN moments scale by 1/512.
__global__ __launch_bounds__(256) void agg_ln(
    const u16* __restrict__ hpb, const int* __restrict__ offs,
    const int2* __restrict__ sedge,
    const float* __restrict__ res, const float* __restrict__ g, const float* __restrict__ b,
    float* __restrict__ out, int nrows) {
  const int wave = threadIdx.x >> 6;
  const int lane = threadIdx.x & 63;
  const int r = blockIdx.x * 4 + wave;
  if (r >= nrows) return;
  const int half = lane >> 5;
  const int f8 = (lane & 31) * 8;

  float acc8[8] = {0.f, 0.f, 0.f, 0.f, 0.f, 0.f, 0.f, 0.f};
  int k = offs[r];
  const int kend = offs[r + 1];
  for (; k + 7 < kend; k += 8) {
    int2 e[4];
#pragma unroll
    for (int j = 0; j < 4; ++j) e[j] = sedge[k + half + 2 * j];
    u16x8 h[4];
#pragma unroll
    for (int j = 0; j < 4; ++j)
      h[j] = *(const u16x8*)(hpb + (size_t)e[j].x * 256 + f8);
#pragma unroll
    for (int j = 0; j < 4; ++j) {
      const float w = __int_as_float(e[j].y);
#pragma unroll
      for (int d = 0; d < 8; ++d) acc8[d] += w * b2f(h[j][d]);
    }
  }
  for (int kc = k + half; kc < kend; kc += 2) {
    const int2 e = sedge[kc];
    const float w = __int_as_float(e.y);
    const u16x8 h = *(const u16x8*)(hpb + (size_t)e.x * 256 + f8);
#pragma unroll
    for (int d = 0; d < 8; ++d) acc8[d] += w * b2f(h[d]);
  }

  // combine the two halves; both now hold identical sums for dims [f8, f8+8)
#pragma unroll
  for (int d = 0; d < 8; ++d) acc8[d] += __shfl_xor(acc8[d], 32);

  // residual (all lanes; duplication accounted by 1/512 scaling)
  {
    const float4 r0 = *(const float4*)(res + (size_t)r * 256 + f8);
    const float4 r1 = *(const float4*)(res + (size_t)r * 256 + f8 + 4);
    acc8[0] += r0.x; acc8[1] += r0.y; acc8[2] += r0.z; acc8[3] += r0.w;
    acc8[4] += r1.x; acc8[5] += r1.y; acc8[6] += r1.z; acc8[7] += r1.w;
  }

  float s = 0.f;
#pragma unroll
  for (int d = 0; d < 8; ++d) s += acc8[d];
#pragma unroll
  for (int m = 32; m >= 1; m >>= 1) s += __shfl_xor(s, m);
  const float mu = s * (1.f / 512.f);   // sums duplicated across halves
#pragma unroll
  for (int d = 0; d < 8; ++d) acc8[d] -= mu;
  float ss = 0.f;
#pragma unroll
  for (int d = 0; d < 8; ++d) ss += acc8[d] * acc8[d];
#pragma unroll
  for (int m = 32; m >= 1; m >>= 1) ss += __shfl_xor(ss, m);
  const float rs = rsqrtf(ss * (1.f / 512.f) + 1e-5f);

  if (half == 0) {
    const float4 g0v = *(const float4*)(g + f8);
    const float4 g1v = *(const float4*)(g + f8 + 4);
    const float4 b0v = *(const float4*)(b + f8);
    const float4 b1v = *(const float4*)(b + f8 + 4);
    float4 o0, o1;
    o0.x = acc8[0] * rs * g0v.x + b0v.x;
    o0.y = acc8[1] * rs * g0v.y + b0v.y;
    o0.z = acc8[2] * rs * g0v.z + b0v.z;
    o0.w = acc8[3] * rs * g0v.w + b0v.w;
    o1.x = acc8[4] * rs * g1v.x + b1v.x;
    o1.y = acc8[5] * rs * g1v.y + b1v.y;
    o1.z = acc8[6] * rs * g1v.z + b1v.z;
    o1.w = acc8[7] * rs * g1v.w + b1v.w;
    *(float4*)(out + (size_t)r * 256 + f8) = o0;
    *(float4*)(out + (size_t)r * 256 + f8 + 4) = o1;
  }
}

extern "C" void kernel_launch(void* const* d_in, const int* in_sizes, int n_in,
                              void* d_out, int out_size, void* d_ws, size_t ws_size,
                              hipStream_t stream) {
  const float* x0    = (const float*)d_in[0];
  const float* x1    = (const float*)d_in[1];
  const float* W0    = (const float*)d_in[2];
  const float* W1    = (const float*)d_in[3];
  const float* Wres1 = (const float*)d_in[4];
  const float* g0    = (const float*)d_in[5];
  const float* b0    = (const float*)d_in[6];
  const float* g1    = (const float*)d_in[7];
  const float* b1    = (const float*)d_in[8];
  const float* ew0   = (const float*)d_in[9];
  const float* ew1   = (const float*)d_in[10];
  const int*   row0  = (const int*)d_in[11];
  const int*   col0  = (const int*)d_in[12];
  const int*   row1  = (const int*)d_in[13];
  const int*   col1  = (const int*)d_in[14];
  float* out = (float*)d_out;

  const int N = 50000, D0 = 256, D1 = 512, DO = 256, E = 1600000;

  // ws layout (bytes, 16B-aligned)
  char* w = (char*)d_ws;
  u16*   hpb   = (u16*)  (w);                  // 25,600,000
  u16*   wtb   = (u16*)  (w + 25600000);       //    262,144 (max 512x256 bf16)
  int2*  sedge = (int2*) (w + 25862144);       // 12,800,000 (packed col+ew, CSR order)
  int*   offs  = (int*)  (w + 38662144);       //    200,004 (N+1)
  int*   ghist = (int*)  (w + 38862160);       //    400,384 (NBUK*EB ints)
  int*   parts = (int*)  (w + 39262560);       //        392
  // tmp aliases hpb: hpb is dead during both CSR builds.
  int2*  tmp   = (int2*) (w);                  // 12,800,000 (aliases hpb)

  float* out0 = out;
  float* out1 = out + (size_t)N * DO;

  const dim3 blk(256);
  const dim3 gemm_grid((N + 63) / 64);         // 782 row-tiles, full DO width each
  const dim3 agg_grid((N + 3) / 4);
  const int NGH = NBUK * EB;                   // 100,096
  const int NBS = (NGH + 1023) / 1024;         // 98

  auto build_csr = [&](const int* row, const int* col, const float* ew) {
    pa_hist<<<dim3(EB), blk, 0, stream>>>(row, ghist, E);
    scan1<<<dim3(NBS), blk, 0, stream>>>(ghist, ghist, parts, NGH);
    scan2<<<dim3(1), dim3(64), 0, stream>>>(parts, NBS);
    scan_add<<<dim3(NBS), blk, 0, stream>>>(ghist, parts, NGH);
    pa_scatter<<<dim3(EB), blk, 0, stream>>>(row, col, ew, ghist, tmp, E);
    pb_sort<<<dim3(NBUK), blk, 0, stream>>>(tmp, ghist, sedge, offs, E, N);
  };

  // ---- type 0: identity residual ----
  build_csr(row0, col0, ew0);
  conv_wt<<<dim3(D0), blk, 0, stream>>>(W0, wtb, D0);
  gemm_bf16<true><<<gemm_grid, blk, 0, stream>>>(x0, wtb, hpb, N, D0);
  agg_ln<<<agg_grid, blk, 0, stream>>>(hpb, offs, sedge, x0, g0, b0, out0, N);

  // ---- type 1: projected residual ----
  conv_wt<<<dim3(D1), blk, 0, stream>>>(Wres1, wtb, D1);
  gemm_bf16<false><<<gemm_grid, blk, 0, stream>>>(x1, wtb, out1, N, D1);
  build_csr(row1, col1, ew1);
  conv_wt<<<dim3(D1), blk, 0, stream>>>(W1, wtb, D1);
  gemm_bf16<true><<<gemm_grid, blk, 0, stream>>>(x1, wtb, hpb, N, D1);
  agg_ln<<<agg_grid, blk, 0, stream>>>(hpb, offs, sedge, out1, g1, b1, out1, N);
}

// Round 5
// 694.452 us; speedup vs baseline: 1.4210x; 1.0186x over previous
//
#include <hip/hip_runtime.h>
#include <hip/hip_bf16.h>
#include <cstddef>

typedef unsigned short u16;
typedef u16 u16x8 __attribute__((ext_vector_type(8)));
typedef __bf16 bf16x8 __attribute__((ext_vector_type(8)));
typedef float f32x4 __attribute__((ext_vector_type(4)));
typedef int i32x4 __attribute__((ext_vector_type(4)));
typedef float f32x4v __attribute__((ext_vector_type(4)));

__device__ __forceinline__ u16 f2b(float f) {
  unsigned int u = __float_as_uint(f);
  unsigned int r = 0x7FFFu + ((u >> 16) & 1u);
  return (u16)((u + r) >> 16);
}
__device__ __forceinline__ float b2f(u16 u) {
  return __uint_as_float(((unsigned int)u) << 16);
}

// ---------------- bf16 MFMA GEMM: C[M,256] = A[M,K](fp32) @ Wt[256,K](bf16)^T --------
// BM=64 x BN=256 tile (full output width per block): each A-tile staged ONCE.
// 256 threads = 4 waves, wave w owns rows 0..63 x cols [64w, 64w+64).
// LDS 40 KB. XOR-swizzled LDS (c ^= row&7) keeps ds_read_b128 conflict-free.
template <bool OUT_BF16>
__global__ __launch_bounds__(256) void gemm_bf16(
    const float* __restrict__ A, const u16* __restrict__ Bt, void* __restrict__ Cv,
    int M, int K) {
  __shared__ u16 As[64 * 64];
  __shared__ u16 Bs[256 * 64];
  const int tid = threadIdx.x;
  const int wid = tid >> 6;
  const int lane = tid & 63;
  const int brow = blockIdx.x * 64;
  const int waveN = wid * 64;
  const int q = lane >> 4;
  const int rl = lane & 15;

  f32x4 acc[4][4] = {};

  const int arow = tid >> 2;         // 0..63
  const int kq = (tid & 3) * 16;     // 0,16,32,48
  const int garow = brow + arow;
  const bool aok = garow < M;
  const int aswz = arow & 7;
  const int brb = tid;               // 0..255
  const int bswz = brb & 7;

  for (int k0 = 0; k0 < K; k0 += 64) {
    {  // stage A (fp32 -> bf16)
      const float* src = A + (size_t)garow * K + k0 + kq;
      u16* dstrow = As + arow * 64;
#pragma unroll
      for (int j = 0; j < 2; ++j) {
        float4 v0 = make_float4(0.f, 0.f, 0.f, 0.f), v1 = v0;
        if (aok) {
          v0 = *(const float4*)(src + j * 8);
          v1 = *(const float4*)(src + j * 8 + 4);
        }
        u16x8 v = {f2b(v0.x), f2b(v0.y), f2b(v0.z), f2b(v0.w),
                   f2b(v1.x), f2b(v1.y), f2b(v1.z), f2b(v1.w)};
        const int c = (kq >> 3) + j;
        *(u16x8*)(dstrow + 8 * (c ^ aswz)) = v;
      }
    }
    {  // stage Bt (already bf16): full 128 B row per thread
      const u16* src = Bt + (size_t)brb * K + k0;
      u16* dstrow = Bs + brb * 64;
#pragma unroll
      for (int j = 0; j < 8; ++j) {
        u16x8 v = *(const u16x8*)(src + j * 8);
        *(u16x8*)(dstrow + 8 * (j ^ bswz)) = v;
      }
    }
    __syncthreads();
#pragma unroll
    for (int ks = 0; ks < 2; ++ks) {
      bf16x8 af[4], bfr[4];
      const int cbase = ks * 4 + q;
#pragma unroll
      for (int i = 0; i < 4; ++i) {
        const int r = 16 * i + rl;
        af[i] = __builtin_bit_cast(bf16x8,
                 *(const u16x8*)(As + r * 64 + 8 * (cbase ^ (rl & 7))));
      }
#pragma unroll
      for (int j = 0; j < 4; ++j) {
        const int r = waveN + 16 * j + rl;
        bfr[j] = __builtin_bit_cast(bf16x8,
                  *(const u16x8*)(Bs + r * 64 + 8 * (cbase ^ (rl & 7))));
      }
#pragma unroll
      for (int i = 0; i < 4; ++i)
#pragma unroll
        for (int j = 0; j < 4; ++j)
          acc[i][j] = __builtin_amdgcn_mfma_f32_16x16x32_bf16(af[i], bfr[j], acc[i][j], 0, 0, 0);
    }
    __syncthreads();
  }

  // epilogue: C/D layout col=lane&15, row=quad*4+reg
#pragma unroll
  for (int i = 0; i < 4; ++i) {
#pragma unroll
    for (int reg = 0; reg < 4; ++reg) {
      const int gr = brow + 16 * i + q * 4 + reg;
      if (gr >= M) continue;
#pragma unroll
      for (int j = 0; j < 4; ++j) {
        const int col = waveN + 16 * j + rl;
        const float v = acc[i][j][reg];
        if (OUT_BF16) ((u16*)Cv)[(size_t)gr * 256 + col] = f2b(v);
        else          ((float*)Cv)[(size_t)gr * 256 + col] = v;
      }
    }
  }
}

// ---------------- W[K][256] fp32 -> Wt[256][K] bf16 ----------------
__global__ __launch_bounds__(256) void conv_wt(const float* __restrict__ W,
                                               u16* __restrict__ Wt, int K) {
  const int idx = blockIdx.x * 256 + threadIdx.x;  // over K*256
  const int k = idx >> 8;
  const int n = idx & 255;
  if (k < K) Wt[(size_t)n * K + k] = f2b(W[idx]);
}

// ---------------- CSR build: two-level counting bucket sort, LDS atomics only -------
#define EB   256   // edge chunks (blocks) for pass A
#define RPB  128   // rows per coarse bucket
#define NBUK 391   // ceil(50048/128); covers rows 0..50047 for N=50000

// per-block edge range, padded to a multiple of 4 for aligned int4 loads
__device__ __forceinline__ void edge_range(int E, int blk, int& s, int& e) {
  const int per = (((E + EB - 1) / EB) + 3) & ~3;
  s = blk * per;
  e = min(E, s + per);
}

__global__ __launch_bounds__(256) void pa_hist(const int* __restrict__ row,
                                               int* __restrict__ ghist, int E) {
  __shared__ int h[NBUK];
  for (int i = threadIdx.x; i < NBUK; i += 256) h[i] = 0;
  __syncthreads();
  int s, e;
  edge_range(E, blockIdx.x, s, e);
  for (int i = s + threadIdx.x * 4; i < e; i += 1024) {
    if (i + 3 < e) {
      const i32x4 rr = __builtin_nontemporal_load((const i32x4*)(row + i));
#pragma unroll
      for (int j = 0; j < 4; ++j) atomicAdd(&h[rr[j] >> 7], 1);
    } else {
      for (int i2 = i; i2 < e; ++i2) atomicAdd(&h[row[i2] >> 7], 1);
    }
  }
  __syncthreads();
  for (int i = threadIdx.x; i < NBUK; i += 256) ghist[i * EB + blockIdx.x] = h[i];
}

__global__ __launch_bounds__(256) void pa_scatter(
    const int* __restrict__ row, const int* __restrict__ col, const float* __restrict__ ew,
    const int* __restrict__ gscan, int2* __restrict__ tmp, int E) {
  __shared__ int cur[NBUK];
  for (int i = threadIdx.x; i < NBUK; i += 256) cur[i] = gscan[i * EB + blockIdx.x];
  __syncthreads();
  int s, e;
  edge_range(E, blockIdx.x, s, e);
  for (int i0 = s + threadIdx.x * 4; i0 < e; i0 += 1024) {
    if (i0 + 3 < e) {
      const i32x4 r4 = __builtin_nontemporal_load((const i32x4*)(row + i0));
      const i32x4 c4 = __builtin_nontemporal_load((const i32x4*)(col + i0));
      const f32x4 w4 = __builtin_nontemporal_load((const f32x4*)(ew + i0));
#pragma unroll
      for (int j = 0; j < 4; ++j) {
        const int pos = atomicAdd(&cur[r4[j] >> 7], 1);
        tmp[pos] = make_int2(((r4[j] & 127) << 16) | c4[j], __float_as_int(w4[j]));
      }
    } else {
      for (int i2 = i0; i2 < e; ++i2) {
        const int r = row[i2];
        const int pos = atomicAdd(&cur[r >> 7], 1);
        tmp[pos] = make_int2(((r & 127) << 16) | col[i2], __float_as_int(ew[i2]));
      }
    }
  }
}

__global__ __launch_bounds__(256) void pb_sort(
    const int2* __restrict__ tmp, const int* __restrict__ gscan,
    int2* __restrict__ sedge, int* __restrict__ offs, int E, int N) {
  __shared__ int h[RPB];
  __shared__ int sc[RPB];
  __shared__ int cur[RPB];
  const int b = blockIdx.x;
  const int t = threadIdx.x;
  const int base = gscan[b * EB];
  const int end = (b == NBUK - 1) ? E : gscan[(b + 1) * EB];
  if (t < RPB) h[t] = 0;
  __syncthreads();
  for (int i = base + t; i < end; i += 256) atomicAdd(&h[(tmp[i].x >> 16) & 127], 1);
  __syncthreads();
  // parallel exclusive scan over the 128 per-row counts (was serial t==0 loop)
  if (t < RPB) sc[t] = h[t];
  __syncthreads();
  for (int off = 1; off < RPB; off <<= 1) {
    int x = (t >= off && t < RPB) ? sc[t - off] : 0;
    __syncthreads();
    if (t < RPB) sc[t] += x;
    __syncthreads();
  }
  if (t < RPB) {
    const int ex = base + sc[t] - h[t];
    cur[t] = ex;
    const int rg = b * RPB + t;
    if (rg <= N) offs[rg] = ex;   // rg==N lands exactly at E
  }
  __syncthreads();
  for (int i = base + t; i < end; i += 256) {
    const int2 v = tmp[i];
    const int pos = atomicAdd(&cur[(v.x >> 16) & 127], 1);
    sedge[pos] = make_int2(v.x & 0xFFFF, v.y);
  }
}

// ---------------- scan helpers ----------------
__global__ __launch_bounds__(256) void scan1(const int* __restrict__ deg,
                                             int* __restrict__ offs,
                                             int* __restrict__ partials, int n) {
  __shared__ int sh[256];
  const int t = threadIdx.x;
  const int base = blockIdx.x * 1024 + t * 4;
  int v[4];
#pragma unroll
  for (int j = 0; j < 4; j++) v[j] = (base + j < n) ? deg[base + j] : 0;
  const int tsum = v[0] + v[1] + v[2] + v[3];
  sh[t] = tsum;
  __syncthreads();
  for (int off = 1; off < 256; off <<= 1) {
    int x = (t >= off) ? sh[t - off] : 0;
    __syncthreads();
    sh[t] += x;
    __syncthreads();
  }
  if (t == 255) partials[blockIdx.x] = sh[255];
  int run = sh[t] - tsum;
#pragma unroll
  for (int j = 0; j < 4; j++) {
    if (base + j < n) offs[base + j] = run;
    run += v[j];
  }
}

__global__ void scan2(int* __restrict__ partials, int nb) {
  if (threadIdx.x == 0 && blockIdx.x == 0) {
    int run = 0;
    for (int i = 0; i < nb; i++) {
      int t = partials[i];
      partials[i] = run;
      run += t;
    }
  }
}

__global__ __launch_bounds__(256) void scan_add(int* __restrict__ a,
                                                const int* __restrict__ partials, int n) {
  const int t = threadIdx.x;
  const int base = blockIdx.x * 1024 + t * 4;
  const int add = partials[blockIdx.x];
#pragma unroll
  for (int j = 0; j < 4; j++)
    if (base + j < n) a[base + j] += add;
}

// ------- fused aggregate (bf16 hp gather) + residual + LayerNorm, 1 wave/row -------
// Two 32-lane halves, each gathering full 512 B rows (u16x8/lane). 16-edge unroll:
// 8 gathers in flight per half. Streaming traffic (sedge, res, out) is marked
// NONTEMPORAL so it doesn't evict the hpb gather table from L2 (the only
// reusable data: 25.6 MB gathered ~32x).
__global__ __launch_bounds__(256) void agg_ln(
    const u16* __restrict__ hpb, const int* __restrict__ offs,
    const int2* __restrict__ sedge,
    const float* __restrict__ res, const float* __restrict__ g, const float* __restrict__ b,
    float* __restrict__ out, int nrows) {
  const int wave = threadIdx.x >> 6;
  const int lane = threadIdx.x & 63;
  const int r = blockIdx.x * 4 + wave;
  if (r >= nrows) return;
  const int half = lane >> 5;
  const int f8 = (lane & 31) * 8;
  const long long* sedge8 = (const long long*)sedge;

  float acc8[8] = {0.f, 0.f, 0.f, 0.f, 0.f, 0.f, 0.f, 0.f};
  int k = offs[r];
  const int kend = offs[r + 1];

  for (; k + 15 < kend; k += 16) {   // 8 gathers in flight per half
    long long e[8];
#pragma unroll
    for (int j = 0; j < 8; ++j)
      e[j] = __builtin_nontemporal_load(sedge8 + k + half + 2 * j);
    u16x8 h[8];
#pragma unroll
    for (int j = 0; j < 8; ++j)
      h[j] = *(const u16x8*)(hpb + (size_t)(int)(e[j] & 0xFFFFFFFFll) * 256 + f8);
#pragma unroll
    for (int j = 0; j < 8; ++j) {
      const float w = __int_as_float((int)(e[j] >> 32));
#pragma unroll
      for (int d = 0; d < 8; ++d) acc8[d] += w * b2f(h[j][d]);
    }
  }
  for (; k + 7 < kend; k += 8) {     // 4 in flight per half
    long long e[4];
#pragma unroll
    for (int j = 0; j < 4; ++j)
      e[j] = __builtin_nontemporal_load(sedge8 + k + half + 2 * j);
    u16x8 h[4];
#pragma unroll
    for (int j = 0; j < 4; ++j)
      h[j] = *(const u16x8*)(hpb + (size_t)(int)(e[j] & 0xFFFFFFFFll) * 256 + f8);
#pragma unroll
    for (int j = 0; j < 4; ++j) {
      const float w = __int_as_float((int)(e[j] >> 32));
#pragma unroll
      for (int d = 0; d < 8; ++d) acc8[d] += w * b2f(h[j][d]);
    }
  }
  for (int kc = k + half; kc < kend; kc += 2) {
    const long long e = sedge8[kc];
    const float w = __int_as_float((int)(e >> 32));
    const u16x8 h = *(const u16x8*)(hpb + (size_t)(int)(e & 0xFFFFFFFFll) * 256 + f8);
#pragma unroll
    for (int d = 0; d < 8; ++d) acc8[d] += w * b2f(h[d]);
  }

  // combine the two halves; both now hold identical sums for dims [f8, f8+8)
#pragma unroll
  for (int d = 0; d < 8; ++d) acc8[d] += __shfl_xor(acc8[d], 32);

  // residual (streamed once -> nontemporal)
  {
    const f32x4 r0 = __builtin_nontemporal_load((const f32x4*)(res + (size_t)r * 256 + f8));
    const f32x4 r1 = __builtin_nontemporal_load((const f32x4*)(res + (size_t)r * 256 + f8 + 4));
#pragma unroll
    for (int d = 0; d < 4; ++d) { acc8[d] += r0[d]; acc8[4 + d] += r1[d]; }
  }

  float s = 0.f;
#pragma unroll
  for (int d = 0; d < 8; ++d) s += acc8[d];
#pragma unroll
  for (int m = 32; m >= 1; m >>= 1) s += __shfl_xor(s, m);
  const float mu = s * (1.f / 512.f);   // sums duplicated across halves
#pragma unroll
  for (int d = 0; d < 8; ++d) acc8[d] -= mu;
  float ss = 0.f;
#pragma unroll
  for (int d = 0; d < 8; ++d) ss += acc8[d] * acc8[d];
#pragma unroll
  for (int m = 32; m >= 1; m >>= 1) ss += __shfl_xor(ss, m);
  const float rs = rsqrtf(ss * (1.f / 512.f) + 1e-5f);

  if (half == 0) {
    const float4 g0v = *(const float4*)(g + f8);
    const float4 g1v = *(const float4*)(g + f8 + 4);
    const float4 b0v = *(const float4*)(b + f8);
    const float4 b1v = *(const float4*)(b + f8 + 4);
    f32x4 o0, o1;
    o0[0] = acc8[0] * rs * g0v.x + b0v.x;
    o0[1] = acc8[1] * rs * g0v.y + b0v.y;
    o0[2] = acc8[2] * rs * g0v.z + b0v.z;
    o0[3] = acc8[3] * rs * g0v.w + b0v.w;
    o1[0] = acc8[4] * rs * g1v.x + b1v.x;
    o1[1] = acc8[5] * rs * g1v.y + b1v.y;
    o1[2] = acc8[6] * rs * g1v.z + b1v.z;
    o1[3] = acc8[7] * rs * g1v.w + b1v.w;
    __builtin_nontemporal_store(o0, (f32x4*)(out + (size_t)r * 256 + f8));
    __builtin_nontemporal_store(o1, (f32x4*)(out + (size_t)r * 256 + f8 + 4));
  }
}

extern "C" void kernel_launch(void* const* d_in, const int* in_sizes, int n_in,
                              void* d_out, int out_size, void* d_ws, size_t ws_size,
                              hipStream_t stream) {
  const float* x0    = (const float*)d_in[0];
  const float* x1    = (const float*)d_in[1];
  const float* W0    = (const float*)d_in[2];
  const float* W1    = (const float*)d_in[3];
  const float* Wres1 = (const float*)d_in[4];
  const float* g0    = (const float*)d_in[5];
  const float* b0    = (const float*)d_in[6];
  const float* g1    = (const float*)d_in[7];
  const float* b1    = (const float*)d_in[8];
  const float* ew0   = (const float*)d_in[9];
  const float* ew1   = (const float*)d_in[10];
  const int*   row0  = (const int*)d_in[11];
  const int*   col0  = (const int*)d_in[12];
  const int*   row1  = (const int*)d_in[13];
  const int*   col1  = (const int*)d_in[14];
  float* out = (float*)d_out;

  const int N = 50000, D0 = 256, D1 = 512, DO = 256, E = 1600000;

  // ws layout (bytes, 16B-aligned)
  char* w = (char*)d_ws;
  u16*   hpb   = (u16*)  (w);                  // 25,600,000
  u16*   wtb   = (u16*)  (w + 25600000);       //    262,144 (max 512x256 bf16)
  int2*  sedge = (int2*) (w + 25862144);       // 12,800,000 (packed col+ew, CSR order)
  int*   offs  = (int*)  (w + 38662144);       //    200,004 (N+1)
  int*   ghist = (int*)  (w + 38862160);       //    400,384 (NBUK*EB ints)
  int*   parts = (int*)  (w + 39262560);       //        392
  // tmp aliases hpb: hpb is dead during both CSR builds.
  int2*  tmp   = (int2*) (w);                  // 12,800,000 (aliases hpb)

  float* out0 = out;
  float* out1 = out + (size_t)N * DO;

  const dim3 blk(256);
  const dim3 gemm_grid((N + 63) / 64);         // 782 row-tiles, full DO width each
  const dim3 agg_grid((N + 3) / 4);
  const int NGH = NBUK * EB;                   // 100,096
  const int NBS = (NGH + 1023) / 1024;         // 98

  auto build_csr = [&](const int* row, const int* col, const float* ew) {
    pa_hist<<<dim3(EB), blk, 0, stream>>>(row, ghist, E);
    scan1<<<dim3(NBS), blk, 0, stream>>>(ghist, ghist, parts, NGH);
    scan2<<<dim3(1), dim3(64), 0, stream>>>(parts, NBS);
    scan_add<<<dim3(NBS), blk, 0, stream>>>(ghist, parts, NGH);
    pa_scatter<<<dim3(EB), blk, 0, stream>>>(row, col, ew, ghist, tmp, E);
    pb_sort<<<dim3(NBUK), blk, 0, stream>>>(tmp, ghist, sedge, offs, E, N);
  };

  // ---- type 0: identity residual ----
  build_csr(row0, col0, ew0);
  conv_wt<<<dim3(D0), blk, 0, stream>>>(W0, wtb, D0);
  gemm_bf16<true><<<gemm_grid, blk, 0, stream>>>(x0, wtb, hpb, N, D0);
  agg_ln<<<agg_grid, blk, 0, stream>>>(hpb, offs, sedge, x0, g0, b0, out0, N);

  // ---- type 1: projected residual ----
  conv_wt<<<dim3(D1), blk, 0, stream>>>(Wres1, wtb, D1);
  gemm_bf16<false><<<gemm_grid, blk, 0, stream>>>(x1, wtb, out1, N, D1);
  build_csr(row1, col1, ew1);
  conv_wt<<<dim3(D1), blk, 0, stream>>>(W1, wtb, D1);
  gemm_bf16<true><<<gemm_grid, blk, 0, stream>>>(x1, wtb, hpb, N, D1);
  agg_ln<<<agg_grid, blk, 0, stream>>>(hpb, offs, sedge, out1, g1, b1, out1, N);
}